// Round 1
// baseline (660.882 us; speedup 1.0000x reference)
//
#include <hip/hip_runtime.h>

// data (262144, 512) fp32, latentZ (1,512) fp32, mu (1,) fp32, tau (1,) fp32.
// Outputs: ir_mu (262144,) then ir_tau (262144,), concatenated flat fp32.
#define ROWS 262144
#define LATENT 512
#define TPB 256
#define BLOCKS 2048
#define TOTAL_WAVES (BLOCKS * (TPB / 64))      // 8192 waves, 8 per SIMD
#define ROWS_PER_WAVE (ROWS / TOTAL_WAVES)     // 32
#define PAIRS (ROWS_PER_WAVE / 2)              // 16 iterations, 2 rows each

// Clang native vector type: accepted by __builtin_nontemporal_load.
typedef float vf4 __attribute__((ext_vector_type(4)));

// Persistent waves, 2 rows per iteration:
//  - 4 vf4 loads in flight per wave (2x the memory-level parallelism of the
//    1-row pipeline) so the HBM latency of the NEXT pair overlaps the
//    butterfly-reduction chain of the CURRENT pair.
//  - 4 independent shuffle-reduce chains (sA,qA,sB,qB) interleave through the
//    6-level butterfly, giving ~4-way ILP on the DS pipe instead of 2-way.
__global__ __launch_bounds__(TPB) void linear_svi_kernel(
    const float* __restrict__ data,
    const float* __restrict__ latentZ,
    const float* __restrict__ mu_p,
    const float* __restrict__ tau_p,
    float* __restrict__ out) {
  const int lane = threadIdx.x & 63;
  const int wave_g = (blockIdx.x << 2) + (threadIdx.x >> 6);  // 0..8191

  const float mu = mu_p[0];
  const float tau = tau_p[0];

  // latentZ fragment: row-invariant, loaded once, L1/L2-resident.
  const vf4* zv = (const vf4*)latentZ;
  const vf4 z0 = zv[lane];
  const vf4 z1 = zv[64 + lane];

  // Rows for this wave: wave_g + k*8192, k=0..31, taken two at a time.
  int rowA = wave_g;
  int rowB = wave_g + TOTAL_WAVES;

  const vf4* pA = (const vf4*)(data + (size_t)rowA * LATENT);
  const vf4* pB = (const vf4*)(data + (size_t)rowB * LATENT);
  vf4 a0 = __builtin_nontemporal_load(pA + lane);
  vf4 a1 = __builtin_nontemporal_load(pA + 64 + lane);
  vf4 b0 = __builtin_nontemporal_load(pB + lane);
  vf4 b1 = __builtin_nontemporal_load(pB + 64 + lane);

  for (int it = 0; it < PAIRS; ++it) {
    // Prefetch the next pair before touching the current pair's dependents.
    vf4 na0 = a0, na1 = a1, nb0 = b0, nb1 = b1;
    const int nrowA = rowA + 2 * TOTAL_WAVES;
    const int nrowB = rowB + 2 * TOTAL_WAVES;
    if (it + 1 < PAIRS) {
      const vf4* npA = (const vf4*)(data + (size_t)nrowA * LATENT);
      const vf4* npB = (const vf4*)(data + (size_t)nrowB * LATENT);
      na0 = __builtin_nontemporal_load(npA + lane);
      na1 = __builtin_nontemporal_load(npA + 64 + lane);
      nb0 = __builtin_nontemporal_load(npB + lane);
      nb1 = __builtin_nontemporal_load(npB + 64 + lane);
    }

    float sA = 0.0f, qA = 0.0f, sB = 0.0f, qB = 0.0f;
    float pr, dd;
#define ACC(ss, qq, zz, xx)    \
    pr = (zz) * (xx);          \
    ss += pr;                  \
    dd = pr - mu;              \
    qq = fmaf(dd, dd, qq);
    ACC(sA, qA, z0.x, a0.x) ACC(sB, qB, z0.x, b0.x)
    ACC(sA, qA, z0.y, a0.y) ACC(sB, qB, z0.y, b0.y)
    ACC(sA, qA, z0.z, a0.z) ACC(sB, qB, z0.z, b0.z)
    ACC(sA, qA, z0.w, a0.w) ACC(sB, qB, z0.w, b0.w)
    ACC(sA, qA, z1.x, a1.x) ACC(sB, qB, z1.x, b1.x)
    ACC(sA, qA, z1.y, a1.y) ACC(sB, qB, z1.y, b1.y)
    ACC(sA, qA, z1.z, a1.z) ACC(sB, qB, z1.z, b1.z)
    ACC(sA, qA, z1.w, a1.w) ACC(sB, qB, z1.w, b1.w)
#undef ACC

    // 64-lane butterfly; 4 independent chains interleave on the DS pipe.
#pragma unroll
    for (int off = 32; off > 0; off >>= 1) {
      sA += __shfl_xor(sA, off, 64);
      sB += __shfl_xor(sB, off, 64);
      qA += __shfl_xor(qA, off, 64);
      qB += __shfl_xor(qB, off, 64);
    }

    // All lanes hold all totals; lanes 0..3 store {ir_muA, ir_tauA,
    // ir_muB, ir_tauB} — one predicated store instruction.
    if (lane < 4) {
      const bool isB = lane >= 2;
      const float s = isB ? sB : sA;
      const float q = isB ? qB : qA;
      const int r = isB ? rowB : rowA;
      const float ir_mu = (s + mu) * (1.0f / 513.0f);
      const float dm = ir_mu - mu;
      const float ir_tau = (tau + 256.0f) / (1.0f + 0.5f * q + dm * dm);
      const float v = (lane & 1) ? ir_tau : ir_mu;
      out[(size_t)(lane & 1) * ROWS + r] = v;
    }

    a0 = na0; a1 = na1; b0 = nb0; b1 = nb1;
    rowA = nrowA; rowB = nrowB;
  }
}

extern "C" void kernel_launch(void* const* d_in, const int* in_sizes, int n_in,
                              void* d_out, int out_size, void* d_ws, size_t ws_size,
                              hipStream_t stream) {
  const float* data    = (const float*)d_in[0];
  const float* latentZ = (const float*)d_in[1];
  const float* mu      = (const float*)d_in[2];
  const float* tau     = (const float*)d_in[3];
  float* out = (float*)d_out;

  linear_svi_kernel<<<dim3(BLOCKS), dim3(TPB), 0, stream>>>(data, latentZ, mu,
                                                            tau, out);
}